// Round 7
// baseline (333.399 us; speedup 1.0000x reference)
//
#include <hip/hip_runtime.h>
#include <math.h>

static constexpr int B = 4, H = 160, W = 160;
static constexpr int HW = H * W;          // 25600
static constexpr int CHW = 64 * HW;       // 1638400
static constexpr int NELEM = B * CHW;     // 6553600

typedef short bf16x8 __attribute__((ext_vector_type(8)));
typedef float f32x4 __attribute__((ext_vector_type(4)));

__device__ __forceinline__ float lrelu(float v) { return v >= 0.f ? v : 0.1f * v; }

__device__ __forceinline__ unsigned short f2bf(float f) {
  unsigned u = __float_as_uint(f);
  return (unsigned short)((u + 0x7FFFu + ((u >> 16) & 1u)) >> 16);  // RNE
}
__device__ __forceinline__ float bf2f(short u) {
  return __uint_as_float(((unsigned)(unsigned short)u) << 16);
}

// ---------------------------------------------------------------------------
// Weight transforms (every call; tiny).
//   w01_bf[o*128+ci]               = bf16(w01[o*128+ci])        (8192 bf16)
//   wb_bf[((ds*9+k)*64+co)*64+ci]  = bf16(aXw[(co*64+ci)*9+k])  (110592 bf16)
//   wd_bf[(k*64+co)*64+ci]         = bf16(dw[(co*64+ci)*9+k])   (36864 bf16)
//   arw_bf[o*192+cp]               = bf16(arw[o*192+cp])        (12288 bf16)
// ---------------------------------------------------------------------------
__global__ __launch_bounds__(256) void k_transform(
    const float* __restrict__ w01, const float* __restrict__ dw,
    const float* __restrict__ arw, const float* __restrict__ a1w,
    const float* __restrict__ a2w, const float* __restrict__ a3w,
    unsigned short* __restrict__ w01_bf, unsigned short* __restrict__ wb_bf,
    unsigned short* __restrict__ wd_bf, unsigned short* __restrict__ arw_bf) {
  int i = blockIdx.x * 256 + threadIdx.x;  // 0 .. 167935
  if (i < 8192) {
    w01_bf[i] = f2bf(w01[i]);  // already [o][ci]
  } else if (i < 118784) {
    int j = i - 8192;
    int ci = j & 63, co = (j >> 6) & 63;
    int kk = j >> 12;              // dsel*9 + k, 0..26
    int dsel = kk / 9; kk -= dsel * 9;
    const float* src = dsel == 0 ? a1w : dsel == 1 ? a2w : a3w;
    wb_bf[j] = f2bf(src[(co * 64 + ci) * 9 + kk]);
  } else if (i < 155648) {
    int j = i - 118784;
    int ci = j & 63, co = (j >> 6) & 63, k = j >> 12;  // k 0..8
    wd_bf[j] = f2bf(dw[(co * 64 + ci) * 9 + k]);
  } else if (i < 167936) {
    int j = i - 155648;
    arw_bf[j] = f2bf(arw[j]);  // already [o][cp]
  }
}

// ---------------------------------------------------------------------------
// Kernel A: MFMA 1x1 conv concat(aux,ref) 128->64 + bias + lrelu.
// M=64 pos, N=64 co, K=128. Inputs staged bf16 pos-major in LDS with XOR
// chunk swizzle (rows stride 144 u16 == 8 words mod 32 -> <=2-way).
// Emits: off0p fp32 POS-major [b][hw][64], off0_bf bf16 pos-major,
// x_bf bf16 pos-major (aux rows read back from the same LDS).
// grid: B*HW/64 = 1600
// ---------------------------------------------------------------------------
__global__ __launch_bounds__(256) void k_conv1x1_mfma(
    const float* __restrict__ aux, const float* __restrict__ ref,
    const unsigned short* __restrict__ w01_bf, const float* __restrict__ b01,
    float* __restrict__ off0p, unsigned short* __restrict__ off0_bf,
    unsigned short* __restrict__ x_bf) {
  __shared__ unsigned short sa[64 * 144];  // 18432 B (epb[64*80] reuses this)
  int pos0 = blockIdx.x * 64;
  int b = pos0 / HW;
  int hw0 = pos0 - b * HW;
  int tid = threadIdx.x;
#pragma unroll 4
  for (int it = 0; it < 32; ++it) {
    int i = it * 256 + tid;
    int ci = i >> 6, p = i & 63;
    float v = (ci < 64) ? aux[b * CHW + ci * HW + hw0 + p]
                        : ref[b * CHW + (ci - 64) * HW + hw0 + p];
    int key = (p >> 2) & 7;
    sa[p * 144 + (((ci >> 3) ^ key) * 8) + (ci & 7)] = f2bf(v);
  }
  __syncthreads();
  int lane = tid & 63, wid = tid >> 6;
  int m = lane & 15, q = lane >> 4;
  f32x4 acc[4] = {};
#pragma unroll
  for (int kc = 0; kc < 4; ++kc) {
    bf16x8 bfrag = *(const bf16x8*)(w01_bf + (wid * 16 + m) * 128 + kc * 32 + q * 8);
#pragma unroll
    for (int mt = 0; mt < 4; ++mt) {
      int row = mt * 16 + m;
      int rkey = (row >> 2) & 7;
      bf16x8 afrag = *(const bf16x8*)(sa + row * 144 + (((kc * 4 + q) ^ rkey) * 8));
      acc[mt] = __builtin_amdgcn_mfma_f32_16x16x32_bf16(afrag, bfrag, acc[mt],
                                                        0, 0, 0);
    }
  }
  // x_bf: aux rows (chunks 0..7) straight out of the staged LDS
#pragma unroll
  for (int it = 0; it < 2; ++it) {
    int u = it * 256 + tid;
    int p = u >> 3, c = u & 7;
    int key = (p >> 2) & 7;
    uint4 v = *(const uint4*)(sa + p * 144 + ((c ^ key) * 8));
    *(uint4*)(x_bf + ((size_t)(b * HW + hw0 + p)) * 64 + c * 8) = v;
  }
  float bi = b01[wid * 16 + m];
  float vv[4][4];
#pragma unroll
  for (int mt = 0; mt < 4; ++mt)
#pragma unroll
    for (int r = 0; r < 4; ++r) {
      float v = lrelu(acc[mt][r] + bi);
      vv[mt][r] = v;  // D: row=pos=q*4+r (in tile mt), col=co=wid*16+m
      off0p[((size_t)(b * HW + hw0 + mt * 16 + q * 4 + r)) * 64 + wid * 16 + m] = v;
    }
  __syncthreads();
  // bf16 repack via LDS (stride 80 u16; chunk-XOR swizzle)
#pragma unroll
  for (int mt = 0; mt < 4; ++mt)
#pragma unroll
    for (int r = 0; r < 4; ++r) {
      int pl = mt * 16 + q * 4 + r;
      int chunk = wid * 2 + (m >> 3);
      int key = (pl >> 2) & 7;
      sa[pl * 80 + ((chunk ^ key) * 8) + (m & 7)] = f2bf(vv[mt][r]);
    }
  __syncthreads();
#pragma unroll
  for (int it = 0; it < 2; ++it) {
    int u = it * 256 + tid;
    int p = u >> 3, c = u & 7;
    int key = (p >> 2) & 7;
    uint4 v = *(const uint4*)(sa + p * 80 + ((c ^ key) * 8));
    *(uint4*)(off0_bf + ((size_t)(b * HW + hw0 + p)) * 64 + c * 8) = v;
  }
}

// ---------------------------------------------------------------------------
// Kernel B: MFMA fused tri-dilation ASPP conv, DIRECT-GLOBAL A operands.
// No input staging: each A fragment is a 16B load from pos-major off0_bf
// (zeroed outside the image); halo reuse served by L2/L3. LDS only for the
// bf16 repack epilogue (stride 80 u16 + XOR swizzle -> <=2-way).
// Output: r_bf[(b*HW+pos)*192 + dsel*64 + co] = lrelu(conv + bias)
// grid: (10, 10, 12)  z = dsel*4 + b
// ---------------------------------------------------------------------------
__global__ __launch_bounds__(256) void k_aspp3_mfma(
    const unsigned short* __restrict__ off0_bf,
    const unsigned short* __restrict__ wb_bf,
    const float* __restrict__ a1b, const float* __restrict__ a2b,
    const float* __restrict__ a3b, unsigned short* __restrict__ r_bf) {
  __shared__ unsigned short epb[256 * 80];  // 40960 B
  int bx = blockIdx.x, by = blockIdx.y;
  int dsel = blockIdx.z >> 2, b = blockIdx.z & 3;
  int d = 1 << dsel;
  const float* bias = dsel == 0 ? a1b : dsel == 1 ? a2b : a3b;
  int tid = threadIdx.x;
  int lane = tid & 63, wid = tid >> 6;
  int m = lane & 15, q = lane >> 4;
  f32x4 acc[4][4] = {};
  const unsigned short* wbase = wb_bf + dsel * 9 * 4096;
  const unsigned short* xoff = off0_bf + (size_t)b * HW * 64;
  int ybase = by * 16 + wid * 4;
  int xcol = bx * 16 + m;

#pragma unroll 3
  for (int k = 0; k < 9; ++k) {
    int ky = k / 3, kx = k - ky * 3;
    int gx = xcol + (kx - 1) * d;
    bool vx = (unsigned)gx < (unsigned)W;
    int gy[4];
    bool vy[4];
#pragma unroll
    for (int mt = 0; mt < 4; ++mt) {
      gy[mt] = ybase + mt + (ky - 1) * d;
      vy[mt] = (unsigned)gy[mt] < (unsigned)H;
    }
#pragma unroll
    for (int ch = 0; ch < 2; ++ch) {
      bf16x8 bfrag[4];
#pragma unroll
      for (int t = 0; t < 4; ++t)
        bfrag[t] =
            *(const bf16x8*)(wbase + (k * 64 + t * 16 + m) * 64 + ch * 32 + q * 8);
      bf16x8 afrag[4];
#pragma unroll
      for (int mt = 0; mt < 4; ++mt) {
        bf16x8 z = {0, 0, 0, 0, 0, 0, 0, 0};
        afrag[mt] = z;
        if (vy[mt] && vx)
          afrag[mt] = *(const bf16x8*)(xoff + ((size_t)(gy[mt] * W + gx)) * 64 +
                                       ch * 32 + q * 8);
      }
#pragma unroll
      for (int mt = 0; mt < 4; ++mt)
#pragma unroll
        for (int t = 0; t < 4; ++t)
          acc[mt][t] = __builtin_amdgcn_mfma_f32_16x16x32_bf16(
              afrag[mt], bfrag[t], acc[mt][t], 0, 0, 0);
    }
  }

  // epilogue: bias + lrelu, bf16 repack via swizzled LDS, 128B global stores
#pragma unroll
  for (int t = 0; t < 4; ++t) {
    float bi = bias[t * 16 + m];
#pragma unroll
    for (int mt = 0; mt < 4; ++mt) {
      int prow = wid * 4 + mt;
#pragma unroll
      for (int r = 0; r < 4; ++r) {
        int pix = prow * 16 + q * 4 + r;  // D: col=lane&15, row=q*4+r
        int chunk = t * 2 + (m >> 3);
        int key = (pix >> 2) & 7;
        epb[pix * 80 + ((chunk ^ key) * 8) + (m & 7)] =
            f2bf(lrelu(acc[mt][t][r] + bi));
      }
    }
  }
  __syncthreads();
  {
    int pix = tid;
    int prow = pix >> 4, pcol = pix & 15;
    int key = (pix >> 2) & 7;
    unsigned short* dst =
        r_bf + ((size_t)(b * HW + (by * 16 + prow) * W + bx * 16 + pcol)) * 192 +
        dsel * 64;
#pragma unroll
    for (int c = 0; c < 8; ++c)
      *(uint4*)(dst + c * 8) = *(const uint4*)(epb + pix * 80 + ((c ^ key) * 8));
  }
}

// ---------------------------------------------------------------------------
// Kernel C: MFMA merge 192->64 (+bias+residual) then offset head 64->18.
// Residual now read from POS-major off0p (fully coalesced).
// grid: B*HW/64 = 1600
// ---------------------------------------------------------------------------
__global__ __launch_bounds__(256) void k_merge_head_mfma(
    const unsigned short* __restrict__ r_bf, const float* __restrict__ off0p,
    const unsigned short* __restrict__ arw_bf, const float* __restrict__ arb,
    const float* __restrict__ w02, const float* __restrict__ b02,
    float* __restrict__ offs) {
  __shared__ unsigned short sa[64 * 200];  // 25600 B; reused as float ep[64*65]
  int pos0 = blockIdx.x * 64;
  int b = pos0 / HW;
  int hw0 = pos0 - b * HW;
  int tid = threadIdx.x;
  const unsigned short* gsrc = r_bf + (size_t)(b * HW + hw0) * 192;
  for (int i = tid; i < 1536; i += 256) {
    int pos = i / 24, c8 = i - pos * 24;
    *(uint4*)(sa + pos * 200 + c8 * 8) = *(const uint4*)(gsrc + i * 8);
  }
  __syncthreads();
  int lane = tid & 63, wid = tid >> 6;
  int m = lane & 15, q = lane >> 4;
  f32x4 acc[4] = {};
#pragma unroll
  for (int kc = 0; kc < 6; ++kc) {
    bf16x8 bfrag = *(const bf16x8*)(arw_bf + (wid * 16 + m) * 192 + kc * 32 + q * 8);
#pragma unroll
    for (int mt = 0; mt < 4; ++mt) {
      bf16x8 afrag = *(const bf16x8*)(sa + (mt * 16 + m) * 200 + kc * 32 + q * 8);
      acc[mt] = __builtin_amdgcn_mfma_f32_16x16x32_bf16(afrag, bfrag, acc[mt],
                                                        0, 0, 0);
    }
  }
  __syncthreads();  // all afrag reads done before overwriting sa
  float* ep = (float*)sa;  // ep[pos*65 + co]
  int co = wid * 16 + m;
  float bi = arb[co];
  const float* resb = off0p + (size_t)(b * HW + hw0) * 64;
#pragma unroll
  for (int mt = 0; mt < 4; ++mt)
#pragma unroll
    for (int r = 0; r < 4; ++r) {
      int pos = mt * 16 + q * 4 + r;  // D: col=co, row=pos
      ep[pos * 65 + co] = acc[mt][r] + bi + resb[pos * 64 + co];
    }
  __syncthreads();
  for (int i = tid; i < 1152; i += 256) {
    int t = i >> 6, p = i & 63;
    const float* w2 = w02 + t * 64;  // t wave-uniform -> s_loads
    float o = b02[t];
#pragma unroll 8
    for (int c = 0; c < 64; ++c) o += ep[p * 65 + c] * w2[c];
    offs[(b * 18 + t) * HW + hw0 + p] = o;
  }
}

// ---------------------------------------------------------------------------
// Kernel E: deformable 3x3 conv, MFMA version (unchanged).
// grid: 1600
// ---------------------------------------------------------------------------
__global__ __launch_bounds__(256) void k_deform_mfma(
    const unsigned short* __restrict__ x_bf, const float* __restrict__ offs,
    const unsigned short* __restrict__ wd_bf, const float* __restrict__ db,
    float* __restrict__ out) {
  constexpr int SP = 72;                       // LDS row stride in bf16
  __shared__ unsigned short sb[2][64 * SP];    // 2 x 9216 B
  int blk = (blockIdx.x & 7) * 200 + (blockIdx.x >> 3);  // XCD slab swizzle
  int pos0 = blk * 64;
  int b = pos0 / HW;
  int hw0 = pos0 - b * HW;
  int tid = threadIdx.x;
  int lane = tid & 63, wid = tid >> 6;
  int m = lane & 15, q = lane >> 4;
  int p = lane;          // sampling position
  int cg = wid;          // sampling ci-group (16 ci)
  int hw = hw0 + p;
  int h = hw / W, wv = hw - h * W;
  const unsigned short* xb = x_bf + (size_t)b * HW * 64;
  const float* ob = offs + b * 18 * HW + hw;
  float offv[18];
#pragma unroll
  for (int j = 0; j < 18; ++j) offv[j] = ob[j * HW];
  f32x4 acc[4] = {};

#pragma unroll
  for (int k = 0; k < 9; ++k) {
    const int ky = k / 3, kx = k - ky * 3;
    float py = offv[2 * k] + (float)(h - 1 + ky);
    float px = offv[2 * k + 1] + (float)(wv - 1 + kx);
    float fy = floorf(py), fx = floorf(px);
    int iy0 = (int)fy, ix0 = (int)fx;
    float wy = py - fy, wx = px - fx;
    int iy1 = iy0 + 1, ix1 = ix0 + 1;
    float vy0 = (iy0 >= 0 && iy0 < H) ? 1.f : 0.f;
    float vy1 = (iy1 >= 0 && iy1 < H) ? 1.f : 0.f;
    float vx0 = (ix0 >= 0 && ix0 < W) ? 1.f : 0.f;
    float vx1 = (ix1 >= 0 && ix1 < W) ? 1.f : 0.f;
    int cy0 = min(max(iy0, 0), H - 1), cy1 = min(max(iy1, 0), H - 1);
    int cx0 = min(max(ix0, 0), W - 1), cx1 = min(max(ix1, 0), W - 1);
    float c00 = vy0 * vx0 * (1.f - wy) * (1.f - wx);
    float c01 = vy0 * vx1 * (1.f - wy) * wx;
    float c10 = vy1 * vx0 * wy * (1.f - wx);
    float c11 = vy1 * vx1 * wy * wx;
    const unsigned short* p00 = xb + (size_t)(cy0 * W + cx0) * 64 + cg * 16;
    const unsigned short* p01 = xb + (size_t)(cy0 * W + cx1) * 64 + cg * 16;
    const unsigned short* p10 = xb + (size_t)(cy1 * W + cx0) * 64 + cg * 16;
    const unsigned short* p11 = xb + (size_t)(cy1 * W + cx1) * 64 + cg * 16;
    unsigned short tb[16];
#pragma unroll
    for (int c2 = 0; c2 < 2; ++c2) {
      bf16x8 v00 = *(const bf16x8*)(p00 + c2 * 8);
      bf16x8 v01 = *(const bf16x8*)(p01 + c2 * 8);
      bf16x8 v10 = *(const bf16x8*)(p10 + c2 * 8);
      bf16x8 v11 = *(const bf16x8*)(p11 + c2 * 8);
#pragma unroll
      for (int j = 0; j < 8; ++j) {
        float sv = c00 * bf2f(v00[j]) + c01 * bf2f(v01[j]) +
                   c10 * bf2f(v10[j]) + c11 * bf2f(v11[j]);
        tb[c2 * 8 + j] = f2bf(sv);
      }
    }
    unsigned short* wr = &sb[k & 1][p * SP + cg * 16];
    *(uint4*)wr = *(const uint4*)&tb[0];
    *(uint4*)(wr + 8) = *(const uint4*)&tb[8];
    __syncthreads();
    const unsigned short* rb = &sb[k & 1][0];
#pragma unroll
    for (int kc = 0; kc < 2; ++kc) {
      bf16x8 bfrag =
          *(const bf16x8*)(wd_bf + (k * 64 + wid * 16 + m) * 64 + kc * 32 + q * 8);
#pragma unroll
      for (int mt = 0; mt < 4; ++mt) {
        bf16x8 afrag = *(const bf16x8*)(rb + (mt * 16 + m) * SP + kc * 32 + q * 8);
        acc[mt] = __builtin_amdgcn_mfma_f32_16x16x32_bf16(afrag, bfrag, acc[mt],
                                                          0, 0, 0);
      }
    }
  }
  int co = wid * 16 + m;
  float bias = db[co];
  size_t orow = (size_t)(b * 64 + co) * HW + hw0;
#pragma unroll
  for (int mt = 0; mt < 4; ++mt)
#pragma unroll
    for (int r = 0; r < 4; ++r)
      out[orow + mt * 16 + q * 4 + r] = acc[mt][r] + bias;  // D: col=co, row=pos
}

// ---------------------------------------------------------------------------
extern "C" void kernel_launch(void* const* d_in, const int* in_sizes, int n_in,
                              void* d_out, int out_size, void* d_ws, size_t ws_size,
                              hipStream_t stream) {
  const float* aux = (const float*)d_in[0];
  const float* ref = (const float*)d_in[1];
  const float* w01 = (const float*)d_in[2];
  const float* b01 = (const float*)d_in[3];
  const float* a1w = (const float*)d_in[4];
  const float* a1b = (const float*)d_in[5];
  const float* a2w = (const float*)d_in[6];
  const float* a2b = (const float*)d_in[7];
  const float* a3w = (const float*)d_in[8];
  const float* a3b = (const float*)d_in[9];
  const float* arw = (const float*)d_in[10];
  const float* arb = (const float*)d_in[11];
  const float* w02 = (const float*)d_in[12];
  const float* b02 = (const float*)d_in[13];
  const float* dw  = (const float*)d_in[14];
  const float* db  = (const float*)d_in[15];
  float* out = (float*)d_out;

  float* off0p = (float*)d_ws;                       // [B,HW,64] fp32 POS-major
  float* offs = off0p + NELEM;                       // [B,18,H,W] fp32
  unsigned short* w01_bf = (unsigned short*)(offs + B * 18 * HW);  // 8192
  unsigned short* off0_bf = w01_bf + 8192;           // [B,HW,64] bf16
  unsigned short* x_bf   = off0_bf + (size_t)NELEM;  // [B,HW,64] bf16
  unsigned short* wb_bf  = x_bf + (size_t)NELEM;     // 110592 bf16
  unsigned short* wd_bf  = wb_bf + 110592;           // 36864 bf16
  unsigned short* arw_bf = wd_bf + 36864;            // 12288 bf16
  unsigned short* r_bf   = arw_bf + 12288;           // [B,HW,192] bf16

  k_transform<<<656, 256, 0, stream>>>(w01, dw, arw, a1w, a2w, a3w,
                                       w01_bf, wb_bf, wd_bf, arw_bf);
  k_conv1x1_mfma<<<B * HW / 64, 256, 0, stream>>>(aux, ref, w01_bf, b01,
                                                  off0p, off0_bf, x_bf);
  k_aspp3_mfma<<<dim3(10, 10, 12), 256, 0, stream>>>(
      off0_bf, wb_bf, a1b, a2b, a3b, r_bf);
  k_merge_head_mfma<<<B * HW / 64, 256, 0, stream>>>(
      r_bf, off0p, arw_bf, arb, w02, b02, offs);
  k_deform_mfma<<<B * HW / 64, 256, 0, stream>>>(x_bf, offs, wd_bf, db, out);
}